// Round 6
// baseline (1037.298 us; speedup 1.0000x reference)
//
#include <hip/hip_runtime.h>
#include <hip/hip_bf16.h>

// R6 theory: the 240us pre-kernel+gap (constant across MODE-2 rounds) costs more than
// the ~45us of inline x-conversion it saves -> drop presplit_x (MODE 1 default).
// Swapped QK^T (a=K,b=Q -> scores^T): softmax k-reduce = 20 in-lane + 2 shfls (was
// 4 rows x 12 shfls); P stores packed uint2 (was 40 scalar shorts).
// Predicted: total ~770us (main ~745, pre ~20), FETCH ~250MB, conflicts ~1.7e7.

constexpr int T  = 6;
constexpr int S  = 66;    // 3*J
constexpr int IN = 256;
constexpr int H  = 8;
constexpr int D  = 32;
constexpr int J  = 22;
constexpr float NEG = -9e15f;
constexpr float INV_SQRT_D = 0.17677669529663688110f; // 1/sqrt(32)

// ---------------- LDS map (bytes), SMEM 49,152 -> 3 blocks/CU ------------------------
// stage (per 64-K chunk): x m01 frag tiles [8 hi|8 lo]x1KB @0..16,384;
//   x m2 tiles (rows 64..95): hi @16,384, lo @20,480 (zero-init once; rows 64/65/chunk);
//   W frag tiles [12 hi|12 lo]x1KB @24,576..49,152.
// attn persistent: qh/ql [66][36] @0/4,752; kh/kl @9,504/14,256 (end 19,008);
//   vTh/vTl bf16[32][104] @27,456/34,112 (208B rows); inv f32[66] @40,768..41,032;
//   aoT bf16[32][104] @41,040..47,696.
// overlays: Ph/Pl bf16[66][104] @0/13,728 (after q/k dead); Wch/Wcl @27,456/34,112 (vT dead).
#define XM2H_OFF 16384
#define XM2L_OFF 20480
#define W_OFF    24576
#define W_LO     12288
#define QH_OFF   0
#define QL_OFF   4752
#define KH_OFF   9504
#define KL_OFF   14256
#define VTH_OFF  27456
#define VTL_OFF  34112
#define INV_OFF  40768
#define AOT_OFF  41040
#define PH_OFF   0
#define PL_OFF   13728
#define WCH_OFF  27456
#define WCL_OFF  34112
#define SMEM_BYTES 49152

// ws: 32 W images (h*4+chunk) of [12 hi|12 lo]x1KB = 24,576 -> 786,432;
// Wc image [hi 32x208B | lo 32x208B] = 13,312 -> 799,744.
#define WSW_STRIDE 24576
#define WSWC_OFF   786432
#define WS_W       799744ull

typedef float f32x4   __attribute__((ext_vector_type(4)));
typedef float f32x16  __attribute__((ext_vector_type(16)));
typedef short bf16x8  __attribute__((ext_vector_type(8)));
typedef short s4v     __attribute__((ext_vector_type(4)));

__device__ __forceinline__ unsigned cvtpk(float a, float b) {
    unsigned r;
    asm("v_cvt_pk_bf16_f32 %0, %1, %2" : "=v"(r) : "v"(a), "v"(b));
    return r;   // low16 = bf16(a), high16 = bf16(b), RNE
}
__device__ __forceinline__ float bfh2f(unsigned short h) {
    return __uint_as_float(((unsigned)h) << 16);
}
__device__ __forceinline__ void split2(float a, float b, unsigned& hi, unsigned& lo) {
    unsigned h = cvtpk(a, b);
    float ra = a - __uint_as_float(h << 16);
    float rb = b - __uint_as_float(h & 0xffff0000u);
    lo = cvtpk(ra, rb);
    hi = h;
}
__device__ __forceinline__ bf16x8 ld_bf16x8_a8(const short* p) {
    s4v a = *(const s4v*)p;
    s4v b = *(const s4v*)(p + 4);
    return __builtin_shufflevector(a, b, 0, 1, 2, 3, 4, 5, 6, 7);
}
__device__ __forceinline__ void gload16(const void* g, void* l) {
    __builtin_amdgcn_global_load_lds(
        (const __attribute__((address_space(1))) unsigned*)g,
        (__attribute__((address_space(3))) unsigned*)l, 16, 0, 0);
}

// ---------------- pre-kernel: W(h,chunk) fragment images + Wc image ------------------
__global__ __launch_bounds__(256)
void presplit_kernel(const float* __restrict__ Wq, const float* __restrict__ Wk,
                     const float* __restrict__ Wv, const float* __restrict__ Wc,
                     unsigned char* __restrict__ ws)
{
    int gid = blockIdx.x * 256 + threadIdx.x;
    if (gid < 49152) {                     // 32 images x 96 rows x 16 col-groups
        int img = gid / 1536, u = gid - img * 1536;
        int row = u >> 4, c = u & 15, k0 = c << 2;
        int mat = row >> 5, dd = row & 31;
        int chunk = img & 3, hh = img >> 2;
        const float* Wm = (mat == 0) ? Wq : (mat == 1) ? Wk : Wv;
        float4 v = *(const float4*)(Wm + (size_t)(hh * 32 + dd) * IN + chunk * 64 + c * 4);
        uint2 hi, lo;
        split2(v.x, v.y, hi.x, lo.x);
        split2(v.z, v.w, hi.y, lo.y);
        int tile  = (mat << 2) + (k0 >> 4);
        int lanei = dd + (((k0 >> 3) & 1) << 5);
        int byte  = (tile << 10) + (lanei << 4) + ((k0 & 7) << 1);
        unsigned char* base = ws + (size_t)img * WSW_STRIDE;
        *(uint2*)(base + byte)        = hi;
        *(uint2*)(base + W_LO + byte) = lo;
    } else if (gid < 49152 + 1664) {       // Wc image: 32 rows x 52 dword cols (zero-padded)
        int g2  = gid - 49152;
        int row = g2 / 52, cu = g2 - row * 52;
        int c0  = 2 * cu;
        float a = (row < 22 && c0     < 66) ? Wc[row * 66 + c0]     : 0.f;
        float b = (row < 22 && c0 + 1 < 66) ? Wc[row * 66 + c0 + 1] : 0.f;
        unsigned hi, lo;
        split2(a, b, hi, lo);
        *(unsigned*)(ws + WSWC_OFF + row * 208 + 4 * cu)        = hi;
        *(unsigned*)(ws + WSWC_OFF + 6656 + row * 208 + 4 * cu) = lo;
    }
}

// MODE: 0 = all inline, 1 = W/Wc presplit (default)
template<int MODE>
__global__ __launch_bounds__(256, 3)
void mha_fused_kernel(const float* __restrict__ x,
                      const float* __restrict__ Wq, const float* __restrict__ bq,
                      const float* __restrict__ Wk, const float* __restrict__ bk,
                      const float* __restrict__ Wv, const float* __restrict__ bv,
                      const float* __restrict__ Wc, const float* __restrict__ bc,
                      const unsigned char* __restrict__ ws,
                      float* __restrict__ out)
{
    __shared__ __align__(16) unsigned char smem[SMEM_BYTES];

    const int tid = threadIdx.x;
    // bt-grouping XCD swizzle: 8 heads of one bt land on one XCD, adjacent in time.
    const int i0  = blockIdx.x;
    const int h   = (i0 >> 3) & 7;
    const int bt  = (i0 & 7) | ((i0 >> 6) << 3);   // bijective over [0,3072)

    const int wid  = tid >> 6;           // wave 0..3
    const int lane = tid & 63;
    const int l15  = lane & 15;
    const int quad = lane >> 4;

    // zero x-m2 tiles once (rows 66..95 stay zero; rows 64/65 rewritten per chunk)
    for (int u = tid; u < 512; u += 256)
        *(uint4*)(smem + XM2H_OFF + u * 16) = (uint4){0u, 0u, 0u, 0u};

    // ---------------- Phase 1: q,k,v projections via split-bf16 32x32x16 MFMA --------
    const f32x16 zacc = {0.f,0.f,0.f,0.f,0.f,0.f,0.f,0.f,0.f,0.f,0.f,0.f,0.f,0.f,0.f,0.f};
    f32x16 accs[3] = {zacc, zacc, zacc};

    const float* xg0 = x + (size_t)bt * S * IN;
    for (int chunk = 0; chunk < 4; ++chunk) {    // K = 4 x 64
        __syncthreads();
        const float* xg = xg0 + chunk * 64;
        if constexpr (MODE == 1) {
            const unsigned char* wimg = ws + (size_t)((h << 2) | chunk) * WSW_STRIDE;
            for (int i = wid; i < 24; i += 4)
                gload16(wimg + (i << 10) + (lane << 4), smem + W_OFF + (i << 10));
        } else {
            for (int u = tid; u < 1536; u += 256) {   // W inline -> fragment-linear
                int row = u >> 4, c = u & 15, k0 = c << 2;
                int mat = row >> 5, dd2 = row & 31;
                const float* Wm = (mat == 0) ? Wq : (mat == 1) ? Wk : Wv;
                float4 v = *(const float4*)(Wm + (size_t)(h * 32 + dd2) * IN + chunk * 64 + c * 4);
                uint2 hi, lo;
                split2(v.x, v.y, hi.x, lo.x);
                split2(v.z, v.w, hi.y, lo.y);
                int tile  = (mat << 2) + (k0 >> 4);
                int lanei = dd2 + (((k0 >> 3) & 1) << 5);
                int byte  = (tile << 10) + (lanei << 4) + ((k0 & 7) << 1);
                *(uint2*)(smem + W_OFF + byte)        = hi;
                *(uint2*)(smem + W_OFF + W_LO + byte) = lo;
            }
        }
        // x inline -> fragment-linear (rows 0..65; 66..95 remain zero from init)
        for (int u = tid; u < 1536; u += 256) {
            int s = u >> 4, c = u & 15, k0 = c << 2;
            if (s >= 66) continue;
            float4 v = *(const float4*)(xg + (size_t)s * IN + c * 4);
            uint2 hi, lo;
            split2(v.x, v.y, hi.x, lo.x);
            split2(v.z, v.w, hi.y, lo.y);
            int ks = k0 >> 4, khalf = (k0 >> 3) & 1, b = (k0 & 7) << 1;
            int off = (ks << 10) + (((s & 31) + (khalf << 5)) << 4) + b;
            if (s < 64) {
                int base = (s >> 5) * 4096 + off;
                *(uint2*)(smem + base)        = hi;
                *(uint2*)(smem + base + 8192) = lo;
            } else {
                *(uint2*)(smem + XM2H_OFF + off) = hi;
                *(uint2*)(smem + XM2L_OFF + off) = lo;
            }
        }
        __syncthreads();

        #pragma unroll
        for (int t = 0; t < 3; ++t) {
            int p = wid + 4 * t;                 // p = mtile*3 + mat, over [0,9)
            if (p >= 9) break;                   // wave-uniform
            int mtile = p / 3, mat = p - mtile * 3;
            const unsigned char *xaH, *xaL;
            if (mtile < 2) { xaH = smem + ((mtile * 4) << 10) + (lane << 4); xaL = xaH + 8192; }
            else           { xaH = smem + XM2H_OFF + (lane << 4);            xaL = xaH + 4096; }
            const unsigned char* wbH = smem + W_OFF + ((mat * 4) << 10) + (lane << 4);
            #pragma unroll
            for (int ks = 0; ks < 4; ++ks) {
                bf16x8 ah = *(const bf16x8*)(xaH + (ks << 10));
                bf16x8 al = *(const bf16x8*)(xaL + (ks << 10));
                bf16x8 bh = *(const bf16x8*)(wbH + (ks << 10));
                bf16x8 bl = *(const bf16x8*)(wbH + (ks << 10) + W_LO);
                accs[t] = __builtin_amdgcn_mfma_f32_32x32x16_bf16(ah, bh, accs[t], 0, 0, 0);
                accs[t] = __builtin_amdgcn_mfma_f32_32x32x16_bf16(ah, bl, accs[t], 0, 0, 0);
                accs[t] = __builtin_amdgcn_mfma_f32_32x32x16_bf16(al, bh, accs[t], 0, 0, 0);
            }
        }
    }
    __syncthreads();   // stage dead; epilogue overwrites it

    // -------- Epilogue: q/k -> hi/lo [s][d]; v -> relu, hi/lo transposed [d][s] ------
    // 32x32 C/D layout: col = lane&31, row = (reg&3) + 8*(reg>>2) + 4*(lane>>5).
    {
        short* qh = (short*)(smem + QH_OFF); short* ql = (short*)(smem + QL_OFF);
        short* kh = (short*)(smem + KH_OFF); short* kl = (short*)(smem + KL_OFF);
        const int dd = lane & 31;
        const int half = lane >> 5;
        #pragma unroll
        for (int t = 0; t < 3; ++t) {
            int p = wid + 4 * t;
            if (p >= 9) break;
            int mtile = p / 3, mat = p - mtile * 3;
            const float* bias_p = (mat == 0) ? bq : (mat == 1) ? bk : bv;
            float bias = bias_p[h * 32 + dd];
            if (mat < 2) {
                short* bh_ = (mat == 0) ? qh : kh;
                short* bl_ = (mat == 0) ? ql : kl;
                #pragma unroll
                for (int g = 0; g < 4; ++g) {
                    int sb2 = mtile * 32 + half * 4 + 8 * g;
                    uint2 hi, lo;
                    split2(accs[t][4*g+0] + bias, accs[t][4*g+1] + bias, hi.x, lo.x);
                    split2(accs[t][4*g+2] + bias, accs[t][4*g+3] + bias, hi.y, lo.y);
                    unsigned hs[4] = { hi.x & 0xffffu, hi.x >> 16, hi.y & 0xffffu, hi.y >> 16 };
                    unsigned ls[4] = { lo.x & 0xffffu, lo.x >> 16, lo.y & 0xffffu, lo.y >> 16 };
                    #pragma unroll
                    for (int r = 0; r < 4; ++r) {
                        int s = sb2 + r;
                        if (s < 66) {
                            bh_[s * 36 + dd] = (short)hs[r];
                            bl_[s * 36 + dd] = (short)ls[r];
                        }
                    }
                }
            } else {
                #pragma unroll
                for (int g = 0; g < 4; ++g) {
                    int sb2 = mtile * 32 + half * 4 + 8 * g;
                    float vv[4];
                    #pragma unroll
                    for (int r = 0; r < 4; ++r) {
                        int s = sb2 + r;
                        vv[r] = (s < 66) ? fmaxf(accs[t][4*g+r] + bias, 0.f) : 0.f;
                    }
                    uint2 ph, pl;
                    split2(vv[0], vv[1], ph.x, pl.x);
                    split2(vv[2], vv[3], ph.y, pl.y);
                    *(uint2*)(smem + VTH_OFF + dd * 208 + 2 * sb2) = ph;
                    *(uint2*)(smem + VTL_OFF + dd * 208 + 2 * sb2) = pl;
                }
            }
        }
    }
    __syncthreads();

    // ------- Phase 3+4 fused, SWAPPED: scores^T = K·Q^T ------------------------------
    // a = k rows (mk strip), b = q rows (mq strip). Output: row k = mk*16+quad*4+reg,
    // col q = mq*16+l15. Per lane: one q, 20 k-values -> k-reduce = in-lane + shfl 16,32.
    {
        const short* qh = (const short*)(smem + QH_OFF);
        const short* ql = (const short*)(smem + QL_OFF);
        const short* kh = (const short*)(smem + KH_OFF);
        const short* kl = (const short*)(smem + KL_OFF);

        auto qk_mfma = [&](int mq, f32x4* acc) {
            int boff = (mq * 16 + l15) * 36 + quad * 8;
            bf16x8 bh = ld_bf16x8_a8(qh + boff);
            bf16x8 bl = ld_bf16x8_a8(ql + boff);
            #pragma unroll
            for (int mk = 0; mk < 5; ++mk) {
                int aoff = (mk * 16 + l15) * 36 + quad * 8;
                bf16x8 ah = ld_bf16x8_a8(kh + aoff);
                bf16x8 al = ld_bf16x8_a8(kl + aoff);
                f32x4 a = (f32x4){0.f, 0.f, 0.f, 0.f};
                a = __builtin_amdgcn_mfma_f32_16x16x32_bf16(ah, bh, a, 0, 0, 0);
                a = __builtin_amdgcn_mfma_f32_16x16x32_bf16(ah, bl, a, 0, 0, 0);
                a = __builtin_amdgcn_mfma_f32_16x16x32_bf16(al, bh, a, 0, 0, 0);
                acc[mk] = a;
            }
        };

        f32x4 accA[5], accB[5];
        qk_mfma(wid, accA);
        if (wid == 3) qk_mfma(4, accB);
        __syncthreads();   // all q/k reads done -> P may overlay q/k

        short* Ph = (short*)(smem + PH_OFF);
        short* Pl = (short*)(smem + PL_OFF);
        float* inv = (float*)(smem + INV_OFF);

        auto sm_store = [&](int mq, f32x4* acc) {
            const int q = mq * 16 + l15;
            float v[5][4];
            #pragma unroll
            for (int mk = 0; mk < 5; ++mk) {
                #pragma unroll
                for (int reg = 0; reg < 4; ++reg) {
                    int k = mk * 16 + quad * 4 + reg;
                    bool invalid = (k >= 66);
                    bool masked = (q < J && k >= 2 * J) || (q >= 2 * J && k < J);
                    float s = acc[mk][reg] * INV_SQRT_D;
                    v[mk][reg] = invalid ? -INFINITY : (masked ? 0.f : s);
                }
            }
            float mm = -INFINITY;
            #pragma unroll
            for (int mk = 0; mk < 5; ++mk)
                #pragma unroll
                for (int reg = 0; reg < 4; ++reg) mm = fmaxf(mm, v[mk][reg]);
            mm = fmaxf(mm, __shfl_xor(mm, 16));
            mm = fmaxf(mm, __shfl_xor(mm, 32));
            const float thr = mm / 9.0f;
            float rm = -INFINITY;
            #pragma unroll
            for (int mk = 0; mk < 5; ++mk) {
                #pragma unroll
                for (int reg = 0; reg < 4; ++reg) {
                    float sv = v[mk][reg];
                    float pr = (fabsf(sv) <= thr) ? NEG : sv;   // -INF sentinels stay below
                    v[mk][reg] = pr;
                    rm = fmaxf(rm, pr);
                }
            }
            rm = fmaxf(rm, __shfl_xor(rm, 16));
            rm = fmaxf(rm, __shfl_xor(rm, 32));
            float e[5][4], lsum = 0.f;
            #pragma unroll
            for (int mk = 0; mk < 5; ++mk) {
                #pragma unroll
                for (int reg = 0; reg < 4; ++reg) {
                    float ev = __expf(v[mk][reg] - rm);   // -INF -> 0
                    e[mk][reg] = ev;
                    lsum += ev;
                }
            }
            lsum += __shfl_xor(lsum, 16);
            lsum += __shfl_xor(lsum, 32);
            if (q < 66) {
                #pragma unroll
                for (int mk = 0; mk < 5; ++mk) {
                    unsigned h0 = cvtpk(e[mk][0], e[mk][1]);
                    unsigned h1 = cvtpk(e[mk][2], e[mk][3]);
                    uint2 hi = {h0, h1}, lo;
                    lo.x = cvtpk(e[mk][0] - bfh2f((unsigned short)h0),
                                 e[mk][1] - bfh2f((unsigned short)(h0 >> 16)));
                    lo.y = cvtpk(e[mk][2] - bfh2f((unsigned short)h1),
                                 e[mk][3] - bfh2f((unsigned short)(h1 >> 16)));
                    int kb = (mk * 16 + quad * 4) * 2;
                    *(uint2*)((unsigned char*)Ph + q * 208 + kb) = hi;
                    *(uint2*)((unsigned char*)Pl + q * 208 + kb) = lo;
                }
                if (quad == 0) inv[q] = 1.0f / lsum;
            }
        };

        sm_store(wid, accA);
        if (wid == 3) sm_store(4, accB);

        // zero P cols 80..95 (rows 0..65): stale LDS there could be NaN-pattern bf16
        for (int u = tid; u < 264; u += 256) {
            int comp = u >= 132 ? 1 : 0, rem = u - comp * 132;
            int row = rem >> 1, part = rem & 1;
            *(uint4*)(smem + (comp ? PL_OFF : PH_OFF) + row * 208 + 160 + part * 16)
                = (uint4){0u, 0u, 0u, 0u};
        }
    }
    __syncthreads();

    // ---------------- Phase 5: aoT = (P @ v)^T * inv, bf16-hi, via MFMA --------------
    {
        const short* Ph = (const short*)(smem + PH_OFF);
        const short* Pl = (const short*)(smem + PL_OFF);
        const short* vh = (const short*)(smem + VTH_OFF);
        const short* vl = (const short*)(smem + VTL_OFF);
        const float* inv = (const float*)(smem + INV_OFF);
        for (int t = 0; t < 3; ++t) {
            int tt = wid + 4 * t;
            if (tt >= 10) break;
            int mq = tt >> 1, nd = tt & 1;
            f32x4 acc = (f32x4){0.f, 0.f, 0.f, 0.f};
            #pragma unroll
            for (int ks = 0; ks < 3; ++ks) {
                bf16x8 a   = *(const bf16x8*)(Ph + (mq * 16 + l15) * 104 + ks * 32 + quad * 8);
                bf16x8 al8 = *(const bf16x8*)(Pl + (mq * 16 + l15) * 104 + ks * 32 + quad * 8);
                bf16x8 b   = *(const bf16x8*)(vh + (nd * 16 + l15) * 104 + ks * 32 + quad * 8);
                bf16x8 bl8 = *(const bf16x8*)(vl + (nd * 16 + l15) * 104 + ks * 32 + quad * 8);
                acc = __builtin_amdgcn_mfma_f32_16x16x32_bf16(a, b, acc, 0, 0, 0);
                acc = __builtin_amdgcn_mfma_f32_16x16x32_bf16(al8, b, acc, 0, 0, 0);
                acc = __builtin_amdgcn_mfma_f32_16x16x32_bf16(a, bl8, acc, 0, 0, 0);
            }
            int dd = nd * 16 + l15, sbase = mq * 16 + quad * 4;
            float o[4];
            #pragma unroll
            for (int reg = 0; reg < 4; ++reg) {
                int qs = sbase + reg;
                o[reg] = (qs < 66) ? acc[reg] * inv[qs] : 0.f;
            }
            uint2 pk;
            pk.x = cvtpk(o[0], o[1]);
            pk.y = cvtpk(o[2], o[3]);
            *(uint2*)(smem + AOT_OFF + dd * 208 + 2 * sbase) = pk;
        }
        // zero aoT cols 80..103
        for (int u = tid; u < 384; u += 256) {
            int row = u / 12, kcol = 80 + 2 * (u % 12);
            *(unsigned*)(smem + AOT_OFF + row * 208 + 2 * kcol) = 0u;
        }
    }
    __syncthreads();

    // ---------------- Stage Wc hi/lo (overlays dead vT) ------------------------------
    if constexpr (MODE >= 1) {
        const unsigned char* wc = ws + WSWC_OFF;   // pre-built 13,312B image
        for (int i = wid; i < 13; i += 4)
            gload16(wc + (i << 10) + (lane << 4), smem + WCH_OFF + (i << 10));
    } else {
        for (int u = tid; u < 726; u += 256) {           // 22 rows x 33 float2
            int row = u / 33, cp = u - row * 33;
            float2 w = *(const float2*)(Wc + row * 66 + 2 * cp);
            unsigned hi, lo;
            split2(w.x, w.y, hi, lo);
            *(unsigned*)(smem + WCH_OFF + row * 208 + 4 * cp) = hi;
            *(unsigned*)(smem + WCL_OFF + row * 208 + 4 * cp) = lo;
        }
        for (int u = tid; u < 836; u += 256) {           // zero cols 66..103, rows 0..21
            int comp = u >= 418 ? 1 : 0, rem = comp ? u - 418 : u;
            int row = rem / 19, kcol = 66 + 2 * (rem % 19);
            *(unsigned*)(smem + (comp ? WCL_OFF : WCH_OFF) + row * 208 + 2 * kcol) = 0u;
        }
    }
    __syncthreads();

    // ---------------- Phase 6: out = Wc @ ao + bc via MFMA ---------------------------
    {
        const short* Wch = (const short*)(smem + WCH_OFF);
        const short* Wcl = (const short*)(smem + WCL_OFF);
        const short* aoT = (const short*)(smem + AOT_OFF);
        int mj = wid >> 1, nd = wid & 1;
        f32x4 acc = (f32x4){0.f, 0.f, 0.f, 0.f};
        #pragma unroll
        for (int ks = 0; ks < 3; ++ks) {
            bf16x8 a   = *(const bf16x8*)(Wch + (mj * 16 + l15) * 104 + ks * 32 + quad * 8);
            bf16x8 al8 = *(const bf16x8*)(Wcl + (mj * 16 + l15) * 104 + ks * 32 + quad * 8);
            bf16x8 b   = *(const bf16x8*)(aoT + (nd * 16 + l15) * 104 + ks * 32 + quad * 8);
            acc = __builtin_amdgcn_mfma_f32_16x16x32_bf16(a, b, acc, 0, 0, 0);
            acc = __builtin_amdgcn_mfma_f32_16x16x32_bf16(al8, b, acc, 0, 0, 0);
        }
        int dd = nd * 16 + l15;
        #pragma unroll
        for (int reg = 0; reg < 4; ++reg) {
            int j = mj * 16 + quad * 4 + reg;
            if (j < 22) {
                size_t o = (size_t)(bt * J + j) * (H * D) + h * 32 + dd;
                out[o] = acc[reg] + bc[j];
            }
        }
    }
}

extern "C" void kernel_launch(void* const* d_in, const int* in_sizes, int n_in,
                              void* d_out, int out_size, void* d_ws, size_t ws_size,
                              hipStream_t stream) {
    const float* x  = (const float*)d_in[0];
    const float* Wq = (const float*)d_in[1];
    const float* bq = (const float*)d_in[2];
    const float* Wk = (const float*)d_in[3];
    const float* bk = (const float*)d_in[4];
    const float* Wv = (const float*)d_in[5];
    const float* bv = (const float*)d_in[6];
    const float* Wc = (const float*)d_in[7];
    const float* bc = (const float*)d_in[8];
    float* out = (float*)d_out;

    const int B = 512;
    dim3 grid(B * T * H), block(256);
    if (d_ws != nullptr && ws_size >= WS_W) {
        hipLaunchKernelGGL(presplit_kernel, dim3(199), dim3(256), 0, stream,
                           Wq, Wk, Wv, Wc, (unsigned char*)d_ws);
        hipLaunchKernelGGL((mha_fused_kernel<1>), grid, block, 0, stream,
                           x, Wq, bq, Wk, bk, Wv, bv, Wc, bc,
                           (const unsigned char*)d_ws, out);
    } else {
        hipLaunchKernelGGL((mha_fused_kernel<0>), grid, block, 0, stream,
                           x, Wq, bq, Wk, bk, Wv, bv, Wc, bc,
                           (const unsigned char*)nullptr, out);
    }
}